// Round 6
// baseline (622.437 us; speedup 1.0000x reference)
//
#include <hip/hip_runtime.h>
#include <math.h>

#define N_USERS 100000
#define NTOT    300000
#define NEDGE   1200000
#define DIM     64
#define NM      (2 * NTOT)                      // unified count array length
#define SCAN_CHUNK 1024
#define NSB     ((NM + SCAN_CHUNK - 1) / SCAN_CHUNK)   // 586

// bucket-staging params
#define NPB     32                              // buckets per side (enc/dec)
#define BROWS   (NTOT / NPB)                    // 9375 rows per bucket
#define CAPE    40960                           // enc bucket capacity (mean 37500, +18 sigma)
#define CAPD    40960
#define CHUNK   2048
#define NB_ENC  ((NEDGE + CHUNK - 1) / CHUNK)   // 586

typedef unsigned short ushort_t;
typedef unsigned int uint_t;

__device__ __forceinline__ float bf2f(ushort_t u) {
    return __uint_as_float(((uint_t)u) << 16);
}
__device__ __forceinline__ ushort_t f2bf(float x) {
    uint_t b = __float_as_uint(x);
    b += 0x7FFFu + ((b >> 16) & 1u);            // round-to-nearest-even
    return (ushort_t)(b >> 16);
}

// Workspace (~247 MB):
//   emb2 (f32, ND) | emb0b (bf16, ND) | emb1b (bf16, ND) | KV (bf16, 2*ND)
//   cursor (2*NTOT int) | penc (int2[E]) | pdec (int[E]) | bsum (1024) | gcurE(32) | gcurD(32)
// Staging (stE int4[32*CAPE], stD int2[32*CAPD], 31.5 MB) aliases the KV
// region — dead until qkv_kernel, which runs after scatter_b.

// ---------------- emb0 -> bf16 table ----------------------------------------
__global__ __launch_bounds__(256) void convert_emb0(
    const float* __restrict__ uE, const float* __restrict__ iE,
    ushort_t* __restrict__ emb0b) {
    int i = blockIdx.x * 256 + threadIdx.x;
    if (i >= NTOT * 16) return;
    float4 x = (i < N_USERS * 16) ? reinterpret_cast<const float4*>(uE)[i]
                                  : reinterpret_cast<const float4*>(iE)[i - N_USERS * 16];
    ushort4 o;
    o.x = f2bf(x.x); o.y = f2bf(x.y); o.z = f2bf(x.z); o.w = f2bf(x.w);
    reinterpret_cast<ushort4*>(emb0b)[i] = o;
}

// ---------------- bucket cursors init ----------------------------------------
__global__ void init_gcur(int* __restrict__ gE, int* __restrict__ gD) {
    int t = threadIdx.x;
    if (t < NPB) { gE[t] = t * CAPE; gD[t] = t * CAPD; }
}

// ---------------- Phase A: bucket staging ------------------------------------
// Block = one 2048-edge chunk of enc (blockIdx<NB_ENC) or dec. LDS-count into
// 32 row-range buckets, reserve one global slot-range per bucket, write packed
// records clustered per bucket (lines fill fast -> write-amp ~1).
__global__ __launch_bounds__(256) void bucket_stage(
    const int* __restrict__ enc_rows, const int* __restrict__ enc_cols,
    const float* __restrict__ enc_vals, const int* __restrict__ dec_rows,
    const int* __restrict__ dec_cols, int* __restrict__ gcurE,
    int* __restrict__ gcurD, int4* __restrict__ stE, int2* __restrict__ stD) {
    __shared__ int cnt[NPB];
    __shared__ int base[NPB];
    __shared__ int run[NPB];
    int t = threadIdx.x;
    bool enc = blockIdx.x < NB_ENC;
    int cb = (enc ? blockIdx.x : blockIdx.x - NB_ENC) * CHUNK;
    int ce = min(cb + CHUNK, NEDGE);
    const int* rows = enc ? enc_rows : dec_rows;
    if (t < NPB) { cnt[t] = 0; run[t] = 0; }
    __syncthreads();
    for (int i = cb + t; i < ce; i += 256) {
        int p = rows[i] / BROWS;
        atomicAdd(&cnt[p], 1);
    }
    __syncthreads();
    if (t < NPB) base[t] = atomicAdd(enc ? &gcurE[t] : &gcurD[t], cnt[t]);
    __syncthreads();
    if (enc) {
        for (int i = cb + t; i < ce; i += 256) {
            int r = enc_rows[i];
            int p = r / BROWS;
            int off = atomicAdd(&run[p], 1);
            int4 v;
            v.x = r; v.y = enc_cols[i]; v.z = __float_as_int(enc_vals[i]); v.w = 0;
            stE[base[p] + off] = v;
        }
    } else {
        for (int i = cb + t; i < ce; i += 256) {
            int r = dec_rows[i];
            int p = r / BROWS;
            int off = atomicAdd(&run[p], 1);
            int2 v; v.x = r; v.y = dec_cols[i];
            stD[base[p] + off] = v;
        }
    }
}

// ---------------- per-bucket histogram ---------------------------------------
// bucket b = blockIdx&63 (b&7 pins XCD); counters slice (37.5 KB) L2-local.
__global__ __launch_bounds__(256) void hist_b(
    const int* __restrict__ gcurE, const int* __restrict__ gcurD,
    const int4* __restrict__ stE, const int2* __restrict__ stD,
    int* __restrict__ cnt) {
    int b = blockIdx.x & 63;
    int sub = blockIdx.x >> 6;
    int nsub = gridDim.x >> 6;
    if (b < NPB) {
        int s = b * CAPE, e = gcurE[b];
        for (int i = s + sub * 256 + threadIdx.x; i < e; i += nsub * 256)
            atomicAdd(&cnt[stE[i].x], 1);
    } else {
        int bb = b - NPB;
        int s = bb * CAPD, e = gcurD[bb];
        for (int i = s + sub * 256 + threadIdx.x; i < e; i += nsub * 256)
            atomicAdd(&cnt[NTOT + stD[i].x], 1);
    }
}

// ---------------- scan (3-kernel exclusive prefix over NM) -------------------
__global__ __launch_bounds__(256) void scan1(const int* __restrict__ cnt,
                                             int* __restrict__ bsum) {
    __shared__ int sh[256];
    int b = blockIdx.x, t = threadIdx.x;
    int base = b * SCAN_CHUNK + t * 4;
    int s = 0;
#pragma unroll
    for (int i = 0; i < 4; ++i) { int idx = base + i; if (idx < NM) s += cnt[idx]; }
    sh[t] = s; __syncthreads();
    for (int off = 1; off < 256; off <<= 1) {
        int x = (t >= off) ? sh[t - off] : 0; __syncthreads();
        sh[t] += x; __syncthreads();
    }
    if (t == 255) bsum[b] = sh[255];
}

__global__ __launch_bounds__(1024) void scan2(int* __restrict__ bsum) {
    __shared__ int sh[1024];
    int t = threadIdx.x;
    int v = (t < NSB) ? bsum[t] : 0;
    sh[t] = v; __syncthreads();
    for (int off = 1; off < 1024; off <<= 1) {
        int x = (t >= off) ? sh[t - off] : 0; __syncthreads();
        sh[t] += x; __syncthreads();
    }
    if (t < NSB) bsum[t] = sh[t] - v;           // exclusive
}

__global__ __launch_bounds__(256) void scan3(int* __restrict__ cnt,
                                             const int* __restrict__ bsum) {
    __shared__ int sh[256];
    int b = blockIdx.x, t = threadIdx.x;
    int base = b * SCAN_CHUNK + t * 4;
    int c[4]; int s = 0;
#pragma unroll
    for (int i = 0; i < 4; ++i) { int idx = base + i; c[i] = (idx < NM) ? cnt[idx] : 0; s += c[i]; }
    sh[t] = s; __syncthreads();
    for (int off = 1; off < 256; off <<= 1) {
        int x = (t >= off) ? sh[t - off] : 0; __syncthreads();
        sh[t] += x; __syncthreads();
    }
    int excl = sh[t] - s + bsum[b];
#pragma unroll
    for (int i = 0; i < 4; ++i) {
        int idx = base + i;
        if (idx < NM) { cnt[idx] = excl; excl += c[i]; }
    }
}

// ---------------- per-bucket scatter -----------------------------------------
// Reads staged slice (L2-streamed, small), scatters into the bucket's CSR
// slice (~300 KB) — both XCD-local -> dirty lines complete before eviction.
__global__ __launch_bounds__(256) void scatter_b(
    const int* __restrict__ gcurE, const int* __restrict__ gcurD,
    const int4* __restrict__ stE, const int2* __restrict__ stD,
    int* __restrict__ cursor, int2* __restrict__ penc, int* __restrict__ pdec) {
    int b = blockIdx.x & 63;
    int sub = blockIdx.x >> 6;
    int nsub = gridDim.x >> 6;
    if (b < NPB) {
        int s = b * CAPE, e = gcurE[b];
        for (int i = s + sub * 256 + threadIdx.x; i < e; i += nsub * 256) {
            int4 v = stE[i];
            int pos = atomicAdd(&cursor[v.x], 1);
            int2 cv; cv.x = v.y; cv.y = v.z;
            penc[pos] = cv;
        }
    } else {
        int bb = b - NPB;
        int s = bb * CAPD, e = gcurD[bb];
        for (int i = s + sub * 256 + threadIdx.x; i < e; i += nsub * 256) {
            int2 v = stD[i];
            int pos = atomicAdd(&cursor[NTOT + v.x], 1);
            pdec[pos - NEDGE] = v.y;
        }
    }
}

// ---------------- GCN layer 1: emb1b[r] = bf16( sum val * emb0b[col] ) ------
__global__ __launch_bounds__(256) void gcn_gather1(
    const int* __restrict__ cursor, const int2* __restrict__ penc,
    const ushort_t* __restrict__ emb0b, ushort_t* __restrict__ emb1b) {
    int t = blockIdx.x * 256 + threadIdx.x;
    int row = t >> 4, l = t & 15;
    if (row >= NTOT) return;
    int s = (row == 0) ? 0 : cursor[row - 1];
    int e = cursor[row];
    float4 acc = {0.f, 0.f, 0.f, 0.f};
    for (int j = s; j < e; ++j) {
        int2 cv = penc[j];
        float v = __int_as_float(cv.y);
        ushort4 xb = reinterpret_cast<const ushort4*>(emb0b + (size_t)cv.x * DIM)[l];
        acc.x += v * bf2f(xb.x); acc.y += v * bf2f(xb.y);
        acc.z += v * bf2f(xb.z); acc.w += v * bf2f(xb.w);
    }
    ushort4 o;
    o.x = f2bf(acc.x); o.y = f2bf(acc.y); o.z = f2bf(acc.z); o.w = f2bf(acc.w);
    reinterpret_cast<ushort4*>(emb1b)[(size_t)row * 16 + l] = o;
}

// ---------------- GCN layer 2 + layer-sum fusion -----------------------------
__global__ __launch_bounds__(256) void gcn_gather2(
    const int* __restrict__ cursor, const int2* __restrict__ penc,
    const ushort_t* __restrict__ emb1b, const float* __restrict__ uE,
    const float* __restrict__ iE, float* __restrict__ emb2,
    float* __restrict__ out) {
    int t = blockIdx.x * 256 + threadIdx.x;
    int row = t >> 4, l = t & 15;
    if (row >= NTOT) return;
    int s = (row == 0) ? 0 : cursor[row - 1];
    int e = cursor[row];
    float4 acc = {0.f, 0.f, 0.f, 0.f};
    for (int j = s; j < e; ++j) {
        int2 cv = penc[j];
        float v = __int_as_float(cv.y);
        ushort4 xb = reinterpret_cast<const ushort4*>(emb1b + (size_t)cv.x * DIM)[l];
        acc.x += v * bf2f(xb.x); acc.y += v * bf2f(xb.y);
        acc.z += v * bf2f(xb.z); acc.w += v * bf2f(xb.w);
    }
    const float* e0p = (row < N_USERS) ? uE + (size_t)row * DIM
                                       : iE + (size_t)(row - N_USERS) * DIM;
    float4 e0 = reinterpret_cast<const float4*>(e0p)[l];
    ushort4 e1b = reinterpret_cast<const ushort4*>(emb1b)[(size_t)row * 16 + l];
    reinterpret_cast<float4*>(emb2)[(size_t)row * 16 + l] = acc;
    float4 o;
    o.x = e0.x + bf2f(e1b.x) + acc.x; o.y = e0.y + bf2f(e1b.y) + acc.y;
    o.z = e0.z + bf2f(e1b.z) + acc.z; o.w = e0.w + bf2f(e1b.w) + acc.w;
    reinterpret_cast<float4*>(out)[(size_t)row * 16 + l] = o;
}

// ---------------- fused Q/K/V = emb2 @ {qT,kT,vT} ----------------------------
__global__ __launch_bounds__(256) void qkv_kernel(
    float* __restrict__ emb2, const float* __restrict__ qT,
    const float* __restrict__ kT, const float* __restrict__ vT,
    ushort_t* __restrict__ KV) {
    __shared__ float lds[4 * 4096];
    float* a_t = lds;
    float* bq = lds + 4096;
    float* bk = lds + 8192;
    float* bv = lds + 12288;
    int t = threadIdx.x;
    int R0 = blockIdx.x * 64;

    {
        const float4* q4 = reinterpret_cast<const float4*>(qT);
        const float4* k4 = reinterpret_cast<const float4*>(kT);
        const float4* v4 = reinterpret_cast<const float4*>(vT);
        float4* lq = reinterpret_cast<float4*>(bq);
        float4* lk = reinterpret_cast<float4*>(bk);
        float4* lv = reinterpret_cast<float4*>(bv);
#pragma unroll
        for (int k = 0; k < 4; ++k) {
            lq[t + k * 256] = q4[t + k * 256];
            lk[t + k * 256] = k4[t + k * 256];
            lv[t + k * 256] = v4[t + k * 256];
        }
    }
    {
        int r = t >> 2, qt = t & 3;
        int grow = R0 + r;
        const float4* src = reinterpret_cast<const float4*>(emb2 + (size_t)grow * DIM);
        bool ok = (grow < NTOT);
#pragma unroll
        for (int k = 0; k < 4; ++k) {
            float4 x;
            if (ok) x = src[qt * 4 + k];
            else { x.x = x.y = x.z = x.w = 0.f; }
            int i0 = qt * 16 + k * 4;
            a_t[(i0 + 0) * 64 + r] = x.x;
            a_t[(i0 + 1) * 64 + r] = x.y;
            a_t[(i0 + 2) * 64 + r] = x.z;
            a_t[(i0 + 3) * 64 + r] = x.w;
        }
    }
    __syncthreads();

    int ty = t >> 4, tx = t & 15;
    float cq[4][4] = {}, ck[4][4] = {}, cv[4][4] = {};
#pragma unroll 4
    for (int i = 0; i < 64; ++i) {
        float4 a = *reinterpret_cast<const float4*>(&a_t[i * 64 + ty * 4]);
        float4 q = *reinterpret_cast<const float4*>(&bq[i * 64 + tx * 4]);
        float4 k = *reinterpret_cast<const float4*>(&bk[i * 64 + tx * 4]);
        float4 v = *reinterpret_cast<const float4*>(&bv[i * 64 + tx * 4]);
        float av[4] = {a.x, a.y, a.z, a.w};
        float qv[4] = {q.x, q.y, q.z, q.w};
        float kv[4] = {k.x, k.y, k.z, k.w};
        float vv[4] = {v.x, v.y, v.z, v.w};
#pragma unroll
        for (int r = 0; r < 4; ++r) {
#pragma unroll
            for (int c = 0; c < 4; ++c) {
                cq[r][c] += av[r] * qv[c];
                ck[r][c] += av[r] * kv[c];
                cv[r][c] += av[r] * vv[c];
            }
        }
    }
    __syncthreads();

#pragma unroll
    for (int r = 0; r < 4; ++r) {
        int grow = R0 + ty * 4 + r;
        if (grow >= NTOT) continue;
        float4 sq;
        sq.x = cq[r][0]; sq.y = cq[r][1]; sq.z = cq[r][2]; sq.w = cq[r][3];
        ushort4 skb, svb;
        skb.x = f2bf(ck[r][0]); skb.y = f2bf(ck[r][1]);
        skb.z = f2bf(ck[r][2]); skb.w = f2bf(ck[r][3]);
        svb.x = f2bf(cv[r][0]); svb.y = f2bf(cv[r][1]);
        svb.z = f2bf(cv[r][2]); svb.w = f2bf(cv[r][3]);
        reinterpret_cast<float4*>(emb2 + (size_t)grow * DIM)[tx] = sq;           // Q
        reinterpret_cast<ushort4*>(KV + (size_t)grow * 128)[tx] = skb;           // K
        reinterpret_cast<ushort4*>(KV + (size_t)grow * 128)[16 + tx] = svb;      // V
    }
}

// ---------------- fused GT, single pass, bf16 KV ------------------------------
__global__ __launch_bounds__(256) void gt_fused(
    const int* __restrict__ cursor, const int* __restrict__ pdec,
    const float* __restrict__ Q, const ushort_t* __restrict__ KV,
    float* __restrict__ out) {
    int t = blockIdx.x * 256 + threadIdx.x;
    int row = t >> 4, l = t & 15;
    if (row >= NTOT) return;
    int s = cursor[NTOT + row - 1] - NEDGE;     // row 0 -> cursor[NTOT-1]==NEDGE -> 0
    int e = cursor[NTOT + row] - NEDGE;
    float4 q = reinterpret_cast<const float4*>(Q)[(size_t)row * 16 + l];
    float norm = 0.f;
    float4 acc = {0.f, 0.f, 0.f, 0.f};
    for (int j = s; j < e; ++j) {
        int c = pdec[j];
        const ushort_t* kvrow = KV + (size_t)c * 128;
        ushort4 kb = reinterpret_cast<const ushort4*>(kvrow)[l];
        ushort4 vb = reinterpret_cast<const ushort4*>(kvrow)[16 + l];
        float p = q.x * bf2f(kb.x) + q.y * bf2f(kb.y)
                + q.z * bf2f(kb.z) + q.w * bf2f(kb.w);
        p += __shfl_xor(p, 1);
        p += __shfl_xor(p, 2);
        p = fminf(10.f, fmaxf(-10.f, p));
        float ex = __expf(p);
        norm += ex;
        acc.x += ex * bf2f(vb.x); acc.y += ex * bf2f(vb.y);
        acc.z += ex * bf2f(vb.z); acc.w += ex * bf2f(vb.w);
    }
    float inv = 1.f / (norm + 1e-8f);
    float4 o = reinterpret_cast<float4*>(out)[(size_t)row * 16 + l];
    o.x += acc.x * inv; o.y += acc.y * inv;
    o.z += acc.z * inv; o.w += acc.w * inv;
    reinterpret_cast<float4*>(out)[(size_t)row * 16 + l] = o;
}

extern "C" void kernel_launch(void* const* d_in, const int* in_sizes, int n_in,
                              void* d_out, int out_size, void* d_ws, size_t ws_size,
                              hipStream_t stream) {
    const float* uE       = (const float*)d_in[0];
    const float* iE       = (const float*)d_in[1];
    const float* qT       = (const float*)d_in[2];
    const float* kT       = (const float*)d_in[3];
    const float* vT       = (const float*)d_in[4];
    const float* enc_vals = (const float*)d_in[5];
    const int*   enc_rows = (const int*)d_in[6];
    const int*   enc_cols = (const int*)d_in[7];
    const int*   dec_rows = (const int*)d_in[8];
    const int*   dec_cols = (const int*)d_in[9];
    float* out = (float*)d_out;

    const size_t ND = (size_t)NTOT * DIM;       // 19.2M
    float*    ws    = (float*)d_ws;
    float*    emb2  = ws;                                   // f32, ND  (becomes Q)
    ushort_t* emb0b = (ushort_t*)(ws + ND);                 // bf16, ND
    ushort_t* emb1b = emb0b + ND;                           // bf16, ND
    ushort_t* KV    = emb1b + ND;                           // bf16, 2*ND
    int*      cursor= (int*)(KV + 2 * ND);                  // 2*NTOT
    int2*     penc  = (int2*)(cursor + NM);                 // NEDGE int2
    int*      pdec  = (int*)(penc + NEDGE);                 // NEDGE int
    int*      bsum  = pdec + NEDGE;                         // 1024
    int*      gcurE = bsum + 1024;                          // 32
    int*      gcurD = gcurE + NPB;                          // 32

    // staging aliases the (currently dead) KV region
    int4*     stE   = (int4*)KV;                            // 32*CAPE int4 (21 MB)
    int2*     stD   = (int2*)(stE + (size_t)NPB * CAPE);    // 32*CAPD int2 (10.5 MB)

    const int GB  = (NTOT * 16) / 256;          // 18750
    const int QB  = (NTOT + 63) / 64;           // 4688
    const int BB  = 2 * NB_ENC;                 // 1172 bucket_stage blocks
    const int HB  = 64 * 16;                    // 1024 hist/scatter blocks

    hipMemsetAsync(cursor, 0, NM * sizeof(int), stream);
    init_gcur<<<1, 64, 0, stream>>>(gcurE, gcurD);
    convert_emb0<<<GB, 256, 0, stream>>>(uE, iE, emb0b);

    bucket_stage<<<BB, 256, 0, stream>>>(enc_rows, enc_cols, enc_vals,
                                         dec_rows, dec_cols, gcurE, gcurD, stE, stD);
    hist_b<<<HB, 256, 0, stream>>>(gcurE, gcurD, stE, stD, cursor);
    scan1<<<NSB, 256, 0, stream>>>(cursor, bsum);
    scan2<<<1, 1024, 0, stream>>>(bsum);
    scan3<<<NSB, 256, 0, stream>>>(cursor, bsum);
    scatter_b<<<HB, 256, 0, stream>>>(gcurE, gcurD, stE, stD, cursor, penc, pdec);

    gcn_gather1<<<GB, 256, 0, stream>>>(cursor, penc, emb0b, emb1b);
    gcn_gather2<<<GB, 256, 0, stream>>>(cursor, penc, emb1b, uE, iE, emb2, out);

    qkv_kernel<<<QB, 256, 0, stream>>>(emb2, qT, kT, vT, KV);
    gt_fused<<<GB, 256, 0, stream>>>(cursor, pdec, emb2, KV, out);
}

// Round 7
// 438.540 us; speedup vs baseline: 1.4193x; 1.4193x over previous
//
#include <hip/hip_runtime.h>
#include <math.h>

#define N_USERS 100000
#define NTOT    300000
#define NEDGE   1200000
#define DIM     64

// bucket sort params
#define NPBS    256                             // buckets per side (enc/dec)
#define BROWS2  1172                            // ceil(NTOT/NPBS)
#define CAPS    5376                            // records/bucket cap (mean 4688, +10 sigma)
#define SCHUNK  4096
#define NCH     ((NEDGE + SCHUNK - 1) / SCHUNK) // 293
#define PAD5    1280                            // 5*256 >= BROWS2

typedef unsigned short ushort_t;
typedef unsigned int uint_t;

__device__ __forceinline__ float bf2f(ushort_t u) {
    return __uint_as_float(((uint_t)u) << 16);
}
__device__ __forceinline__ ushort_t f2bf(float x) {
    uint_t b = __float_as_uint(x);
    b += 0x7FFFu + ((b >> 16) & 1u);            // round-to-nearest-even
    return (ushort_t)(b >> 16);
}

// Workspace (~247 MB):
//   emb2 (f32, ND) | emb0b (bf16, ND) | emb1b (bf16, ND) | KV (bf16, 2*ND)
//   rsE (NTOT+1 int) | rsD (NTOT+1 int) | penc (int2[E]) | pdec (int[E])
//   gcurE/gcurD/bbE/bbD (256 each)
// Staging stE (int2[256*CAPS], 11 MB) + stD (int[256*CAPS], 5.5 MB) aliases
// the KV region (dead until qkv_kernel, which runs after sort_b).

// ---------------- emb0 -> bf16 table ----------------------------------------
__global__ __launch_bounds__(256) void convert_emb0(
    const float* __restrict__ uE, const float* __restrict__ iE,
    ushort_t* __restrict__ emb0b) {
    int i = blockIdx.x * 256 + threadIdx.x;
    if (i >= NTOT * 16) return;
    float4 x = (i < N_USERS * 16) ? reinterpret_cast<const float4*>(uE)[i]
                                  : reinterpret_cast<const float4*>(iE)[i - N_USERS * 16];
    ushort4 o;
    o.x = f2bf(x.x); o.y = f2bf(x.y); o.z = f2bf(x.z); o.w = f2bf(x.w);
    reinterpret_cast<ushort4*>(emb0b)[i] = o;
}

// ---------------- bucket cursors init ----------------------------------------
__global__ void init_gcur(int* __restrict__ gE, int* __restrict__ gD) {
    int t = threadIdx.x;
    gE[t] = t * CAPS;
    gD[t] = t * CAPS;
}

// ---------------- Phase A: bucket staging (packed records) -------------------
// Block = one 4096-edge chunk of enc or dec. LDS-count into 256 row-range
// buckets, reserve slots, write packed records clustered per bucket.
// enc record: int2{ (localrow<<19)|col, val_bits }; dec record: int packed.
__global__ __launch_bounds__(256) void bucket_stage(
    const int* __restrict__ enc_rows, const int* __restrict__ enc_cols,
    const float* __restrict__ enc_vals, const int* __restrict__ dec_rows,
    const int* __restrict__ dec_cols, int* __restrict__ gcurE,
    int* __restrict__ gcurD, int2* __restrict__ stE, int* __restrict__ stD) {
    __shared__ int cnt[NPBS];
    __shared__ int base[NPBS];
    __shared__ int run[NPBS];
    int t = threadIdx.x;
    bool enc = blockIdx.x < NCH;
    int cb = (enc ? blockIdx.x : blockIdx.x - NCH) * SCHUNK;
    int ce = min(cb + SCHUNK, NEDGE);
    const int* rows = enc ? enc_rows : dec_rows;
    cnt[t] = 0; run[t] = 0;
    __syncthreads();
    for (int i = cb + t; i < ce; i += 256) atomicAdd(&cnt[rows[i] / BROWS2], 1);
    __syncthreads();
    base[t] = atomicAdd(enc ? &gcurE[t] : &gcurD[t], cnt[t]);
    __syncthreads();
    if (enc) {
        for (int i = cb + t; i < ce; i += 256) {
            int r = rows[i];
            int p = r / BROWS2;
            int off = atomicAdd(&run[p], 1);
            int2 v;
            v.x = ((r - p * BROWS2) << 19) | enc_cols[i];
            v.y = __float_as_int(enc_vals[i]);
            stE[base[p] + off] = v;
        }
    } else {
        for (int i = cb + t; i < ce; i += 256) {
            int r = rows[i];
            int p = r / BROWS2;
            int off = atomicAdd(&run[p], 1);
            stD[base[p] + off] = ((r - p * BROWS2) << 19) | dec_cols[i];
        }
    }
}

// ---------------- bucket-count scan (one block) ------------------------------
__global__ __launch_bounds__(256) void scanB(
    const int* __restrict__ gcurE, const int* __restrict__ gcurD,
    int* __restrict__ bbE, int* __restrict__ bbD,
    int* __restrict__ rsE, int* __restrict__ rsD) {
    __shared__ int sh[256];
    int t = threadIdx.x;
    int c = gcurE[t] - t * CAPS;
    sh[t] = c; __syncthreads();
    for (int off = 1; off < 256; off <<= 1) {
        int x = (t >= off) ? sh[t - off] : 0; __syncthreads();
        sh[t] += x; __syncthreads();
    }
    bbE[t] = sh[t] - c;
    __syncthreads();
    int cd = gcurD[t] - t * CAPS;
    sh[t] = cd; __syncthreads();
    for (int off = 1; off < 256; off <<= 1) {
        int x = (t >= off) ? sh[t - off] : 0; __syncthreads();
        sh[t] += x; __syncthreads();
    }
    bbD[t] = sh[t] - cd;
    if (t == 0) { rsE[NTOT] = NEDGE; rsD[NTOT] = NEDGE; }
}

// ---------------- per-bucket LDS counting sort -------------------------------
// One block per bucket: LDS hist -> LDS scan -> LDS scatter -> coalesced flush
// of the sorted CSR segment + per-row start offsets. No random global writes.
__global__ __launch_bounds__(256) void sort_b(
    const int* __restrict__ gcurE, const int* __restrict__ gcurD,
    const int* __restrict__ bbE, const int* __restrict__ bbD,
    const int2* __restrict__ stE, const int* __restrict__ stD,
    int2* __restrict__ penc, int* __restrict__ pdec,
    int* __restrict__ rsE, int* __restrict__ rsD) {
    __shared__ int cnt[PAD5];
    __shared__ int rowst[PAD5];
    __shared__ int tsum[256];
    __shared__ int2 outb[CAPS];
    int t = threadIdx.x;
    bool enc = blockIdx.x < NPBS;
    int b = enc ? blockIdx.x : blockIdx.x - NPBS;
    int rowbase = b * BROWS2;
    int s = b * CAPS;
    int e = enc ? gcurE[b] : gcurD[b];
    int gbase = enc ? bbE[b] : bbD[b];
    int n = e - s;

    for (int i = t; i < PAD5; i += 256) cnt[i] = 0;
    __syncthreads();
    if (enc) {
        for (int i = s + t; i < e; i += 256)
            atomicAdd(&cnt[((uint_t)stE[i].x) >> 19], 1);
    } else {
        for (int i = s + t; i < e; i += 256)
            atomicAdd(&cnt[((uint_t)stD[i]) >> 19], 1);
    }
    __syncthreads();
    int b5 = t * 5, sum = 0;
#pragma unroll
    for (int k = 0; k < 5; ++k) { int c = cnt[b5 + k]; rowst[b5 + k] = sum; sum += c; }
    tsum[t] = sum; __syncthreads();
    for (int off = 1; off < 256; off <<= 1) {
        int x = (t >= off) ? tsum[t - off] : 0; __syncthreads();
        tsum[t] += x; __syncthreads();
    }
    int excl = tsum[t] - sum;
#pragma unroll
    for (int k = 0; k < 5; ++k) {
        rowst[b5 + k] += excl;
        cnt[b5 + k] = rowst[b5 + k];            // cnt becomes the scatter cursor
    }
    __syncthreads();

    if (enc) {
        for (int i = s + t; i < e; i += 256) {
            int2 v = stE[i];
            int lr = ((uint_t)v.x) >> 19;
            int pos = atomicAdd(&cnt[lr], 1);
            outb[pos] = make_int2(v.x & 0x7FFFF, v.y);
        }
        __syncthreads();
        for (int i = t; i < n; i += 256) penc[gbase + i] = outb[i];
        int nrows = min(BROWS2, NTOT - rowbase);
        for (int j = t; j < nrows; j += 256) rsE[rowbase + j] = gbase + rowst[j];
    } else {
        int* ob = (int*)outb;
        for (int i = s + t; i < e; i += 256) {
            int v = stD[i];
            int pos = atomicAdd(&cnt[((uint_t)v) >> 19], 1);
            ob[pos] = v & 0x7FFFF;
        }
        __syncthreads();
        for (int i = t; i < n; i += 256) pdec[gbase + i] = ob[i];
        int nrows = min(BROWS2, NTOT - rowbase);
        for (int j = t; j < nrows; j += 256) rsD[rowbase + j] = gbase + rowst[j];
    }
}

// ---------------- GCN layer 1: emb1b[r] = bf16( sum val * emb0b[col] ) ------
__global__ __launch_bounds__(256) void gcn_gather1(
    const int* __restrict__ rsE, const int2* __restrict__ penc,
    const ushort_t* __restrict__ emb0b, ushort_t* __restrict__ emb1b) {
    int t = blockIdx.x * 256 + threadIdx.x;
    int row = t >> 4, l = t & 15;
    if (row >= NTOT) return;
    int s = rsE[row], e = rsE[row + 1];
    float4 acc = {0.f, 0.f, 0.f, 0.f};
    for (int j = s; j < e; ++j) {
        int2 cv = penc[j];
        float v = __int_as_float(cv.y);
        ushort4 xb = reinterpret_cast<const ushort4*>(emb0b + (size_t)cv.x * DIM)[l];
        acc.x += v * bf2f(xb.x); acc.y += v * bf2f(xb.y);
        acc.z += v * bf2f(xb.z); acc.w += v * bf2f(xb.w);
    }
    ushort4 o;
    o.x = f2bf(acc.x); o.y = f2bf(acc.y); o.z = f2bf(acc.z); o.w = f2bf(acc.w);
    reinterpret_cast<ushort4*>(emb1b)[(size_t)row * 16 + l] = o;
}

// ---------------- GCN layer 2 + layer-sum fusion -----------------------------
__global__ __launch_bounds__(256) void gcn_gather2(
    const int* __restrict__ rsE, const int2* __restrict__ penc,
    const ushort_t* __restrict__ emb1b, const float* __restrict__ uE,
    const float* __restrict__ iE, float* __restrict__ emb2,
    float* __restrict__ out) {
    int t = blockIdx.x * 256 + threadIdx.x;
    int row = t >> 4, l = t & 15;
    if (row >= NTOT) return;
    int s = rsE[row], e = rsE[row + 1];
    float4 acc = {0.f, 0.f, 0.f, 0.f};
    for (int j = s; j < e; ++j) {
        int2 cv = penc[j];
        float v = __int_as_float(cv.y);
        ushort4 xb = reinterpret_cast<const ushort4*>(emb1b + (size_t)cv.x * DIM)[l];
        acc.x += v * bf2f(xb.x); acc.y += v * bf2f(xb.y);
        acc.z += v * bf2f(xb.z); acc.w += v * bf2f(xb.w);
    }
    const float* e0p = (row < N_USERS) ? uE + (size_t)row * DIM
                                       : iE + (size_t)(row - N_USERS) * DIM;
    float4 e0 = reinterpret_cast<const float4*>(e0p)[l];
    ushort4 e1b = reinterpret_cast<const ushort4*>(emb1b)[(size_t)row * 16 + l];
    reinterpret_cast<float4*>(emb2)[(size_t)row * 16 + l] = acc;
    float4 o;
    o.x = e0.x + bf2f(e1b.x) + acc.x; o.y = e0.y + bf2f(e1b.y) + acc.y;
    o.z = e0.z + bf2f(e1b.z) + acc.z; o.w = e0.w + bf2f(e1b.w) + acc.w;
    reinterpret_cast<float4*>(out)[(size_t)row * 16 + l] = o;
}

// ---------------- fused Q/K/V = emb2 @ {qT,kT,vT} ----------------------------
__global__ __launch_bounds__(256) void qkv_kernel(
    float* __restrict__ emb2, const float* __restrict__ qT,
    const float* __restrict__ kT, const float* __restrict__ vT,
    ushort_t* __restrict__ KV) {
    __shared__ float lds[4 * 4096];
    float* a_t = lds;
    float* bq = lds + 4096;
    float* bk = lds + 8192;
    float* bv = lds + 12288;
    int t = threadIdx.x;
    int R0 = blockIdx.x * 64;

    {
        const float4* q4 = reinterpret_cast<const float4*>(qT);
        const float4* k4 = reinterpret_cast<const float4*>(kT);
        const float4* v4 = reinterpret_cast<const float4*>(vT);
        float4* lq = reinterpret_cast<float4*>(bq);
        float4* lk = reinterpret_cast<float4*>(bk);
        float4* lv = reinterpret_cast<float4*>(bv);
#pragma unroll
        for (int k = 0; k < 4; ++k) {
            lq[t + k * 256] = q4[t + k * 256];
            lk[t + k * 256] = k4[t + k * 256];
            lv[t + k * 256] = v4[t + k * 256];
        }
    }
    {
        int r = t >> 2, qt = t & 3;
        int grow = R0 + r;
        const float4* src = reinterpret_cast<const float4*>(emb2 + (size_t)grow * DIM);
        bool ok = (grow < NTOT);
#pragma unroll
        for (int k = 0; k < 4; ++k) {
            float4 x;
            if (ok) x = src[qt * 4 + k];
            else { x.x = x.y = x.z = x.w = 0.f; }
            int i0 = qt * 16 + k * 4;
            a_t[(i0 + 0) * 64 + r] = x.x;
            a_t[(i0 + 1) * 64 + r] = x.y;
            a_t[(i0 + 2) * 64 + r] = x.z;
            a_t[(i0 + 3) * 64 + r] = x.w;
        }
    }
    __syncthreads();

    int ty = t >> 4, tx = t & 15;
    float cq[4][4] = {}, ck[4][4] = {}, cv[4][4] = {};
#pragma unroll 4
    for (int i = 0; i < 64; ++i) {
        float4 a = *reinterpret_cast<const float4*>(&a_t[i * 64 + ty * 4]);
        float4 q = *reinterpret_cast<const float4*>(&bq[i * 64 + tx * 4]);
        float4 k = *reinterpret_cast<const float4*>(&bk[i * 64 + tx * 4]);
        float4 v = *reinterpret_cast<const float4*>(&bv[i * 64 + tx * 4]);
        float av[4] = {a.x, a.y, a.z, a.w};
        float qv[4] = {q.x, q.y, q.z, q.w};
        float kv[4] = {k.x, k.y, k.z, k.w};
        float vv[4] = {v.x, v.y, v.z, v.w};
#pragma unroll
        for (int r = 0; r < 4; ++r) {
#pragma unroll
            for (int c = 0; c < 4; ++c) {
                cq[r][c] += av[r] * qv[c];
                ck[r][c] += av[r] * kv[c];
                cv[r][c] += av[r] * vv[c];
            }
        }
    }
    __syncthreads();

#pragma unroll
    for (int r = 0; r < 4; ++r) {
        int grow = R0 + ty * 4 + r;
        if (grow >= NTOT) continue;
        float4 sq;
        sq.x = cq[r][0]; sq.y = cq[r][1]; sq.z = cq[r][2]; sq.w = cq[r][3];
        ushort4 skb, svb;
        skb.x = f2bf(ck[r][0]); skb.y = f2bf(ck[r][1]);
        skb.z = f2bf(ck[r][2]); skb.w = f2bf(ck[r][3]);
        svb.x = f2bf(cv[r][0]); svb.y = f2bf(cv[r][1]);
        svb.z = f2bf(cv[r][2]); svb.w = f2bf(cv[r][3]);
        reinterpret_cast<float4*>(emb2 + (size_t)grow * DIM)[tx] = sq;           // Q
        reinterpret_cast<ushort4*>(KV + (size_t)grow * 128)[tx] = skb;           // K
        reinterpret_cast<ushort4*>(KV + (size_t)grow * 128)[16 + tx] = svb;      // V
    }
}

// ---------------- fused GT, single pass, bf16 KV ------------------------------
__global__ __launch_bounds__(256) void gt_fused(
    const int* __restrict__ rsD, const int* __restrict__ pdec,
    const float* __restrict__ Q, const ushort_t* __restrict__ KV,
    float* __restrict__ out) {
    int t = blockIdx.x * 256 + threadIdx.x;
    int row = t >> 4, l = t & 15;
    if (row >= NTOT) return;
    int s = rsD[row], e = rsD[row + 1];
    float4 q = reinterpret_cast<const float4*>(Q)[(size_t)row * 16 + l];
    float norm = 0.f;
    float4 acc = {0.f, 0.f, 0.f, 0.f};
    for (int j = s; j < e; ++j) {
        int c = pdec[j];
        const ushort_t* kvrow = KV + (size_t)c * 128;
        ushort4 kb = reinterpret_cast<const ushort4*>(kvrow)[l];
        ushort4 vb = reinterpret_cast<const ushort4*>(kvrow)[16 + l];
        float p = q.x * bf2f(kb.x) + q.y * bf2f(kb.y)
                + q.z * bf2f(kb.z) + q.w * bf2f(kb.w);
        p += __shfl_xor(p, 1);
        p += __shfl_xor(p, 2);
        p = fminf(10.f, fmaxf(-10.f, p));
        float ex = __expf(p);
        norm += ex;
        acc.x += ex * bf2f(vb.x); acc.y += ex * bf2f(vb.y);
        acc.z += ex * bf2f(vb.z); acc.w += ex * bf2f(vb.w);
    }
    float inv = 1.f / (norm + 1e-8f);
    float4 o = reinterpret_cast<float4*>(out)[(size_t)row * 16 + l];
    o.x += acc.x * inv; o.y += acc.y * inv;
    o.z += acc.z * inv; o.w += acc.w * inv;
    reinterpret_cast<float4*>(out)[(size_t)row * 16 + l] = o;
}

extern "C" void kernel_launch(void* const* d_in, const int* in_sizes, int n_in,
                              void* d_out, int out_size, void* d_ws, size_t ws_size,
                              hipStream_t stream) {
    const float* uE       = (const float*)d_in[0];
    const float* iE       = (const float*)d_in[1];
    const float* qT       = (const float*)d_in[2];
    const float* kT       = (const float*)d_in[3];
    const float* vT       = (const float*)d_in[4];
    const float* enc_vals = (const float*)d_in[5];
    const int*   enc_rows = (const int*)d_in[6];
    const int*   enc_cols = (const int*)d_in[7];
    const int*   dec_rows = (const int*)d_in[8];
    const int*   dec_cols = (const int*)d_in[9];
    float* out = (float*)d_out;

    const size_t ND = (size_t)NTOT * DIM;       // 19.2M
    float*    ws    = (float*)d_ws;
    float*    emb2  = ws;                                   // f32, ND (becomes Q)
    ushort_t* emb0b = (ushort_t*)(ws + ND);                 // bf16, ND
    ushort_t* emb1b = emb0b + ND;                           // bf16, ND
    ushort_t* KV    = emb1b + ND;                           // bf16, 2*ND
    int*      rsE   = (int*)(KV + 2 * ND);                  // NTOT+1
    int*      rsD   = rsE + NTOT + 1;                       // NTOT+1
    int2*     penc  = (int2*)(rsD + NTOT + 1);              // NEDGE int2
    int*      pdec  = (int*)(penc + NEDGE);                 // NEDGE int
    int*      gcurE = pdec + NEDGE;                         // 256
    int*      gcurD = gcurE + NPBS;                         // 256
    int*      bbE   = gcurD + NPBS;                         // 256
    int*      bbD   = bbE + NPBS;                           // 256

    // staging aliases the (currently dead) KV region
    int2*     stE   = (int2*)KV;                            // 256*CAPS int2 (11 MB)
    int*      stD   = (int*)(stE + (size_t)NPBS * CAPS);    // 256*CAPS int (5.5 MB)

    const int GB  = (NTOT * 16) / 256;          // 18750
    const int QB  = (NTOT + 63) / 64;           // 4688

    init_gcur<<<1, 256, 0, stream>>>(gcurE, gcurD);
    convert_emb0<<<GB, 256, 0, stream>>>(uE, iE, emb0b);

    bucket_stage<<<2 * NCH, 256, 0, stream>>>(enc_rows, enc_cols, enc_vals,
                                              dec_rows, dec_cols, gcurE, gcurD, stE, stD);
    scanB<<<1, 256, 0, stream>>>(gcurE, gcurD, bbE, bbD, rsE, rsD);
    sort_b<<<2 * NPBS, 256, 0, stream>>>(gcurE, gcurD, bbE, bbD, stE, stD,
                                         penc, pdec, rsE, rsD);

    gcn_gather1<<<GB, 256, 0, stream>>>(rsE, penc, emb0b, emb1b);
    gcn_gather2<<<GB, 256, 0, stream>>>(rsE, penc, emb1b, uE, iE, emb2, out);

    qkv_kernel<<<QB, 256, 0, stream>>>(emb2, qT, kT, vT, KV);
    gt_fused<<<GB, 256, 0, stream>>>(rsD, pdec, emb2, KV, out);
}

// Round 8
// 409.716 us; speedup vs baseline: 1.5192x; 1.0704x over previous
//
#include <hip/hip_runtime.h>
#include <math.h>

#define N_USERS 100000
#define NTOT    300000
#define NEDGE   1200000
#define DIM     64

// bucket sort params
#define NPBS    256                             // buckets per side (enc/dec)
#define BROWS2  1172                            // ceil(NTOT/NPBS)
#define CAPS    5376                            // records/bucket cap
#define SCHUNK  4096
#define NCH     ((NEDGE + SCHUNK - 1) / SCHUNK) // 293
#define PAD5    1280                            // 5*256 >= BROWS2

typedef unsigned short ushort_t;
typedef unsigned int uint_t;
typedef __attribute__((ext_vector_type(8))) short short8;
typedef __attribute__((ext_vector_type(4))) float f32x4;

__device__ __forceinline__ float bf2f(ushort_t u) {
    return __uint_as_float(((uint_t)u) << 16);
}
__device__ __forceinline__ ushort_t f2bf(float x) {
    uint_t b = __float_as_uint(x);
    b += 0x7FFFu + ((b >> 16) & 1u);            // round-to-nearest-even
    return (ushort_t)(b >> 16);
}

// Workspace (~209 MB):
//   emb0b (bf16 ND) | emb1b (bf16 ND)   <- Q (f32 ND) aliases both after they die
//   emb2b (bf16 ND) | KV (bf16 2*ND)    <- staging stE/stD aliases KV front
//   Bt (3*4096 bf16) | rsE | rsD | penc | pdec | gcurE/gcurD/bbE/bbD

// ---------------- emb0 -> bf16 table ----------------------------------------
__global__ __launch_bounds__(256) void convert_emb0(
    const float* __restrict__ uE, const float* __restrict__ iE,
    ushort_t* __restrict__ emb0b) {
    int i = blockIdx.x * 256 + threadIdx.x;
    if (i >= NTOT * 16) return;
    float4 x = (i < N_USERS * 16) ? reinterpret_cast<const float4*>(uE)[i]
                                  : reinterpret_cast<const float4*>(iE)[i - N_USERS * 16];
    ushort4 o;
    o.x = f2bf(x.x); o.y = f2bf(x.y); o.z = f2bf(x.z); o.w = f2bf(x.w);
    reinterpret_cast<ushort4*>(emb0b)[i] = o;
}

// ---------------- qT/kT/vT -> transposed bf16 Bt[c][k] ----------------------
__global__ void bt_prep(const float* __restrict__ qT, const float* __restrict__ kT,
                        const float* __restrict__ vT, ushort_t* __restrict__ Bt) {
    int t = threadIdx.x;
    for (int idx = t; idx < 4096; idx += 256) {
        int k = idx >> 6, c = idx & 63;
        Bt[c * 64 + k]        = f2bf(qT[idx]);
        Bt[4096 + c * 64 + k] = f2bf(kT[idx]);
        Bt[8192 + c * 64 + k] = f2bf(vT[idx]);
    }
}

// ---------------- bucket cursors init ----------------------------------------
__global__ void init_gcur(int* __restrict__ gE, int* __restrict__ gD) {
    int t = threadIdx.x;
    gE[t] = t * CAPS;
    gD[t] = t * CAPS;
}

// ---------------- Phase A: bucket staging (packed records) -------------------
__global__ __launch_bounds__(256) void bucket_stage(
    const int* __restrict__ enc_rows, const int* __restrict__ enc_cols,
    const float* __restrict__ enc_vals, const int* __restrict__ dec_rows,
    const int* __restrict__ dec_cols, int* __restrict__ gcurE,
    int* __restrict__ gcurD, int2* __restrict__ stE, int* __restrict__ stD) {
    __shared__ int cnt[NPBS];
    __shared__ int base[NPBS];
    __shared__ int run[NPBS];
    int t = threadIdx.x;
    bool enc = blockIdx.x < NCH;
    int cb = (enc ? blockIdx.x : blockIdx.x - NCH) * SCHUNK;
    int ce = min(cb + SCHUNK, NEDGE);
    const int* rows = enc ? enc_rows : dec_rows;
    cnt[t] = 0; run[t] = 0;
    __syncthreads();
    for (int i = cb + t; i < ce; i += 256) atomicAdd(&cnt[rows[i] / BROWS2], 1);
    __syncthreads();
    base[t] = atomicAdd(enc ? &gcurE[t] : &gcurD[t], cnt[t]);
    __syncthreads();
    if (enc) {
        for (int i = cb + t; i < ce; i += 256) {
            int r = rows[i];
            int p = r / BROWS2;
            int off = atomicAdd(&run[p], 1);
            int2 v;
            v.x = ((r - p * BROWS2) << 19) | enc_cols[i];
            v.y = __float_as_int(enc_vals[i]);
            stE[base[p] + off] = v;
        }
    } else {
        for (int i = cb + t; i < ce; i += 256) {
            int r = rows[i];
            int p = r / BROWS2;
            int off = atomicAdd(&run[p], 1);
            stD[base[p] + off] = ((r - p * BROWS2) << 19) | dec_cols[i];
        }
    }
}

// ---------------- bucket-count scan (one block) ------------------------------
__global__ __launch_bounds__(256) void scanB(
    const int* __restrict__ gcurE, const int* __restrict__ gcurD,
    int* __restrict__ bbE, int* __restrict__ bbD,
    int* __restrict__ rsE, int* __restrict__ rsD) {
    __shared__ int sh[256];
    int t = threadIdx.x;
    int c = gcurE[t] - t * CAPS;
    sh[t] = c; __syncthreads();
    for (int off = 1; off < 256; off <<= 1) {
        int x = (t >= off) ? sh[t - off] : 0; __syncthreads();
        sh[t] += x; __syncthreads();
    }
    bbE[t] = sh[t] - c;
    __syncthreads();
    int cd = gcurD[t] - t * CAPS;
    sh[t] = cd; __syncthreads();
    for (int off = 1; off < 256; off <<= 1) {
        int x = (t >= off) ? sh[t - off] : 0; __syncthreads();
        sh[t] += x; __syncthreads();
    }
    bbD[t] = sh[t] - cd;
    if (t == 0) { rsE[NTOT] = NEDGE; rsD[NTOT] = NEDGE; }
}

// ---------------- per-bucket LDS counting sort -------------------------------
__global__ __launch_bounds__(256) void sort_b(
    const int* __restrict__ gcurE, const int* __restrict__ gcurD,
    const int* __restrict__ bbE, const int* __restrict__ bbD,
    const int2* __restrict__ stE, const int* __restrict__ stD,
    int2* __restrict__ penc, int* __restrict__ pdec,
    int* __restrict__ rsE, int* __restrict__ rsD) {
    __shared__ int cnt[PAD5];
    __shared__ int rowst[PAD5];
    __shared__ int tsum[256];
    __shared__ int2 outb[CAPS];
    int t = threadIdx.x;
    bool enc = blockIdx.x < NPBS;
    int b = enc ? blockIdx.x : blockIdx.x - NPBS;
    int rowbase = b * BROWS2;
    int s = b * CAPS;
    int e = enc ? gcurE[b] : gcurD[b];
    int gbase = enc ? bbE[b] : bbD[b];
    int n = e - s;

    for (int i = t; i < PAD5; i += 256) cnt[i] = 0;
    __syncthreads();
    if (enc) {
        for (int i = s + t; i < e; i += 256)
            atomicAdd(&cnt[((uint_t)stE[i].x) >> 19], 1);
    } else {
        for (int i = s + t; i < e; i += 256)
            atomicAdd(&cnt[((uint_t)stD[i]) >> 19], 1);
    }
    __syncthreads();
    int b5 = t * 5, sum = 0;
#pragma unroll
    for (int k = 0; k < 5; ++k) { int c = cnt[b5 + k]; rowst[b5 + k] = sum; sum += c; }
    tsum[t] = sum; __syncthreads();
    for (int off = 1; off < 256; off <<= 1) {
        int x = (t >= off) ? tsum[t - off] : 0; __syncthreads();
        tsum[t] += x; __syncthreads();
    }
    int excl = tsum[t] - sum;
#pragma unroll
    for (int k = 0; k < 5; ++k) {
        rowst[b5 + k] += excl;
        cnt[b5 + k] = rowst[b5 + k];            // cnt becomes the scatter cursor
    }
    __syncthreads();

    if (enc) {
        for (int i = s + t; i < e; i += 256) {
            int2 v = stE[i];
            int lr = ((uint_t)v.x) >> 19;
            int pos = atomicAdd(&cnt[lr], 1);
            outb[pos] = make_int2(v.x & 0x7FFFF, v.y);
        }
        __syncthreads();
        for (int i = t; i < n; i += 256) penc[gbase + i] = outb[i];
        int nrows = min(BROWS2, NTOT - rowbase);
        for (int j = t; j < nrows; j += 256) rsE[rowbase + j] = gbase + rowst[j];
    } else {
        int* ob = (int*)outb;
        for (int i = s + t; i < e; i += 256) {
            int v = stD[i];
            int pos = atomicAdd(&cnt[((uint_t)v) >> 19], 1);
            ob[pos] = v & 0x7FFFF;
        }
        __syncthreads();
        for (int i = t; i < n; i += 256) pdec[gbase + i] = ob[i];
        int nrows = min(BROWS2, NTOT - rowbase);
        for (int j = t; j < nrows; j += 256) rsD[rowbase + j] = gbase + rowst[j];
    }
}

// ---------------- GCN layer 1: emb1b[r] = bf16( sum val * emb0b[col] ) ------
__global__ __launch_bounds__(256) void gcn_gather1(
    const int* __restrict__ rsE, const int2* __restrict__ penc,
    const ushort_t* __restrict__ emb0b, ushort_t* __restrict__ emb1b) {
    int t = blockIdx.x * 256 + threadIdx.x;
    int row = t >> 4, l = t & 15;
    if (row >= NTOT) return;
    int s = rsE[row], e = rsE[row + 1];
    float4 acc = {0.f, 0.f, 0.f, 0.f};
    for (int j = s; j < e; ++j) {
        int2 cv = penc[j];
        float v = __int_as_float(cv.y);
        ushort4 xb = reinterpret_cast<const ushort4*>(emb0b + (size_t)cv.x * DIM)[l];
        acc.x += v * bf2f(xb.x); acc.y += v * bf2f(xb.y);
        acc.z += v * bf2f(xb.z); acc.w += v * bf2f(xb.w);
    }
    ushort4 o;
    o.x = f2bf(acc.x); o.y = f2bf(acc.y); o.z = f2bf(acc.z); o.w = f2bf(acc.w);
    reinterpret_cast<ushort4*>(emb1b)[(size_t)row * 16 + l] = o;
}

// ---------------- GCN layer 2 + layer-sum fusion (emb2 now bf16) -------------
__global__ __launch_bounds__(256) void gcn_gather2(
    const int* __restrict__ rsE, const int2* __restrict__ penc,
    const ushort_t* __restrict__ emb1b, const float* __restrict__ uE,
    const float* __restrict__ iE, ushort_t* __restrict__ emb2b,
    float* __restrict__ out) {
    int t = blockIdx.x * 256 + threadIdx.x;
    int row = t >> 4, l = t & 15;
    if (row >= NTOT) return;
    int s = rsE[row], e = rsE[row + 1];
    float4 acc = {0.f, 0.f, 0.f, 0.f};
    for (int j = s; j < e; ++j) {
        int2 cv = penc[j];
        float v = __int_as_float(cv.y);
        ushort4 xb = reinterpret_cast<const ushort4*>(emb1b + (size_t)cv.x * DIM)[l];
        acc.x += v * bf2f(xb.x); acc.y += v * bf2f(xb.y);
        acc.z += v * bf2f(xb.z); acc.w += v * bf2f(xb.w);
    }
    const float* e0p = (row < N_USERS) ? uE + (size_t)row * DIM
                                       : iE + (size_t)(row - N_USERS) * DIM;
    float4 e0 = reinterpret_cast<const float4*>(e0p)[l];
    ushort4 e1b = reinterpret_cast<const ushort4*>(emb1b)[(size_t)row * 16 + l];
    ushort4 o2;
    o2.x = f2bf(acc.x); o2.y = f2bf(acc.y); o2.z = f2bf(acc.z); o2.w = f2bf(acc.w);
    reinterpret_cast<ushort4*>(emb2b)[(size_t)row * 16 + l] = o2;
    float4 o;
    o.x = e0.x + bf2f(e1b.x) + acc.x; o.y = e0.y + bf2f(e1b.y) + acc.y;
    o.z = e0.z + bf2f(e1b.z) + acc.z; o.w = e0.w + bf2f(e1b.w) + acc.w;
    reinterpret_cast<float4*>(out)[(size_t)row * 16 + l] = o;
}

// ---------------- MFMA Q/K/V: [NTOT x 64] bf16 @ 3x [64 x 64] bf16 -----------
// No LDS. Wave w of each block owns 64 rows. A-frags from global (row-major
// emb2b), B-frags from transposed Bt (L2-hot). Q f32, K/V bf16 interleaved.
// Layouts (HW-verified m89/m91): A row=lane&15,k=(lane>>4)*8+j; B col=lane&15,
// same k; C/D col=lane&15, row=(lane>>4)*4+reg.
__global__ __launch_bounds__(256) void qkv_mfma(
    const ushort_t* __restrict__ emb2b, const ushort_t* __restrict__ Bt,
    float* __restrict__ Q, ushort_t* __restrict__ KV) {
    int tid = threadIdx.x;
    int w = tid >> 6, lane = tid & 63;
    int lr = lane & 15, lh = lane >> 4;
    int R0 = blockIdx.x * 256 + w * 64;

    short8 a[4][2];
    short8 z8 = {0, 0, 0, 0, 0, 0, 0, 0};
#pragma unroll
    for (int m = 0; m < 4; ++m) {
        int row = R0 + m * 16 + lr;
        if (row < NTOT) {
            const ushort_t* ap = emb2b + (size_t)row * 64 + lh * 8;
            a[m][0] = *reinterpret_cast<const short8*>(ap);
            a[m][1] = *reinterpret_cast<const short8*>(ap + 32);
        } else {
            a[m][0] = z8; a[m][1] = z8;
        }
    }

#pragma unroll
    for (int n = 0; n < 4; ++n) {
        int col = n * 16 + lr;
        const ushort_t* bp = Bt + (size_t)col * 64 + lh * 8;
        short8 bq0 = *reinterpret_cast<const short8*>(bp);
        short8 bq1 = *reinterpret_cast<const short8*>(bp + 32);
        short8 bk0 = *reinterpret_cast<const short8*>(bp + 4096);
        short8 bk1 = *reinterpret_cast<const short8*>(bp + 4096 + 32);
        short8 bv0 = *reinterpret_cast<const short8*>(bp + 8192);
        short8 bv1 = *reinterpret_cast<const short8*>(bp + 8192 + 32);
#pragma unroll
        for (int m = 0; m < 4; ++m) {
            f32x4 aq = {0.f, 0.f, 0.f, 0.f};
            f32x4 ak = {0.f, 0.f, 0.f, 0.f};
            f32x4 av = {0.f, 0.f, 0.f, 0.f};
            aq = __builtin_amdgcn_mfma_f32_16x16x32_bf16(a[m][0], bq0, aq, 0, 0, 0);
            aq = __builtin_amdgcn_mfma_f32_16x16x32_bf16(a[m][1], bq1, aq, 0, 0, 0);
            ak = __builtin_amdgcn_mfma_f32_16x16x32_bf16(a[m][0], bk0, ak, 0, 0, 0);
            ak = __builtin_amdgcn_mfma_f32_16x16x32_bf16(a[m][1], bk1, ak, 0, 0, 0);
            av = __builtin_amdgcn_mfma_f32_16x16x32_bf16(a[m][0], bv0, av, 0, 0, 0);
            av = __builtin_amdgcn_mfma_f32_16x16x32_bf16(a[m][1], bv1, av, 0, 0, 0);
            int rbase = R0 + m * 16 + lh * 4;
#pragma unroll
            for (int r = 0; r < 4; ++r) {
                int srow = rbase + r;
                if (srow < NTOT) {
                    Q[(size_t)srow * 64 + col] = aq[r];
                    KV[(size_t)srow * 128 + col] = f2bf(ak[r]);
                    KV[(size_t)srow * 128 + 64 + col] = f2bf(av[r]);
                }
            }
        }
    }
}

// ---------------- fused GT, single pass, bf16 KV ------------------------------
__global__ __launch_bounds__(256) void gt_fused(
    const int* __restrict__ rsD, const int* __restrict__ pdec,
    const float* __restrict__ Q, const ushort_t* __restrict__ KV,
    float* __restrict__ out) {
    int t = blockIdx.x * 256 + threadIdx.x;
    int row = t >> 4, l = t & 15;
    if (row >= NTOT) return;
    int s = rsD[row], e = rsD[row + 1];
    float4 q = reinterpret_cast<const float4*>(Q)[(size_t)row * 16 + l];
    float norm = 0.f;
    float4 acc = {0.f, 0.f, 0.f, 0.f};
    for (int j = s; j < e; ++j) {
        int c = pdec[j];
        const ushort_t* kvrow = KV + (size_t)c * 128;
        ushort4 kb = reinterpret_cast<const ushort4*>(kvrow)[l];
        ushort4 vb = reinterpret_cast<const ushort4*>(kvrow)[16 + l];
        float p = q.x * bf2f(kb.x) + q.y * bf2f(kb.y)
                + q.z * bf2f(kb.z) + q.w * bf2f(kb.w);
        p += __shfl_xor(p, 1);
        p += __shfl_xor(p, 2);
        p = fminf(10.f, fmaxf(-10.f, p));
        float ex = __expf(p);
        norm += ex;
        acc.x += ex * bf2f(vb.x); acc.y += ex * bf2f(vb.y);
        acc.z += ex * bf2f(vb.z); acc.w += ex * bf2f(vb.w);
    }
    float inv = 1.f / (norm + 1e-8f);
    float4 o = reinterpret_cast<float4*>(out)[(size_t)row * 16 + l];
    o.x += acc.x * inv; o.y += acc.y * inv;
    o.z += acc.z * inv; o.w += acc.w * inv;
    reinterpret_cast<float4*>(out)[(size_t)row * 16 + l] = o;
}

extern "C" void kernel_launch(void* const* d_in, const int* in_sizes, int n_in,
                              void* d_out, int out_size, void* d_ws, size_t ws_size,
                              hipStream_t stream) {
    const float* uE       = (const float*)d_in[0];
    const float* iE       = (const float*)d_in[1];
    const float* qT       = (const float*)d_in[2];
    const float* kT       = (const float*)d_in[3];
    const float* vT       = (const float*)d_in[4];
    const float* enc_vals = (const float*)d_in[5];
    const int*   enc_rows = (const int*)d_in[6];
    const int*   enc_cols = (const int*)d_in[7];
    const int*   dec_rows = (const int*)d_in[8];
    const int*   dec_cols = (const int*)d_in[9];
    float* out = (float*)d_out;

    const size_t ND = (size_t)NTOT * DIM;       // 19.2M
    ushort_t* emb0b = (ushort_t*)d_ws;                      // bf16, ND
    ushort_t* emb1b = emb0b + ND;                           // bf16, ND
    ushort_t* emb2b = emb1b + ND;                           // bf16, ND
    ushort_t* KV    = emb2b + ND;                           // bf16, 2*ND
    ushort_t* Bt    = KV + 2 * ND;                          // bf16, 3*4096
    int*      rsE   = (int*)(Bt + 3 * 4096);                // NTOT+1
    int*      rsD   = rsE + NTOT + 1;                       // NTOT+1
    int2*     penc  = (int2*)(rsD + NTOT + 1);              // NEDGE int2
    int*      pdec  = (int*)(penc + NEDGE);                 // NEDGE int
    int*      gcurE = pdec + NEDGE;                         // 256
    int*      gcurD = gcurE + NPBS;                         // 256
    int*      bbE   = gcurD + NPBS;                         // 256
    int*      bbD   = bbE + NPBS;                           // 256

    float*    Q     = (float*)emb0b;            // aliases emb0b+emb1b (dead by qkv)
    int2*     stE   = (int2*)KV;                // staging aliases KV (dead until qkv)
    int*      stD   = (int*)(stE + (size_t)NPBS * CAPS);

    const int GB  = (NTOT * 16) / 256;          // 18750
    const int QB  = (NTOT + 255) / 256;         // 1172

    init_gcur<<<1, 256, 0, stream>>>(gcurE, gcurD);
    convert_emb0<<<GB, 256, 0, stream>>>(uE, iE, emb0b);
    bt_prep<<<1, 256, 0, stream>>>(qT, kT, vT, Bt);

    bucket_stage<<<2 * NCH, 256, 0, stream>>>(enc_rows, enc_cols, enc_vals,
                                              dec_rows, dec_cols, gcurE, gcurD, stE, stD);
    scanB<<<1, 256, 0, stream>>>(gcurE, gcurD, bbE, bbD, rsE, rsD);
    sort_b<<<2 * NPBS, 256, 0, stream>>>(gcurE, gcurD, bbE, bbD, stE, stD,
                                         penc, pdec, rsE, rsD);

    gcn_gather1<<<GB, 256, 0, stream>>>(rsE, penc, emb0b, emb1b);
    gcn_gather2<<<GB, 256, 0, stream>>>(rsE, penc, emb1b, uE, iE, emb2b, out);

    qkv_mfma<<<QB, 256, 0, stream>>>(emb2b, Bt, Q, KV);
    gt_fused<<<GB, 256, 0, stream>>>(rsD, pdec, Q, KV, out);
}